// Round 12
// baseline (362.254 us; speedup 1.0000x reference)
//
#include <hip/hip_runtime.h>

#define NN    100000
#define NE    1600000
#define BSH   9            // 512 nodes per bucket
#define BSZ   512
#define NBK   196          // ceil(NN/512)
#define TA    8192         // edges per binA chunk-block
#define NBA   196          // ceil(NE/TA)
#define CAP2R 8960         // per-bucket raw edge capacity (mean 8163, +8.8 sigma)
#define CAP2  9472         // per-bucket capacity incl. self-loops (CAP2R + 512)
#define NBG   782          // gemm1 blocks
#define WPAD  136          // Wt LDS row pitch (halves): 272B -> bank stride 4, 2-way max
#define RLN2  1.4426950408889634f

typedef _Float16 half_t;
typedef __attribute__((ext_vector_type(2))) _Float16 f16x2;
typedef __attribute__((ext_vector_type(4))) _Float16 f16x4;
typedef __attribute__((ext_vector_type(8))) _Float16 f16x8;
typedef __attribute__((ext_vector_type(4))) float    f32x4;

__device__ inline float fast_exp2(float x) {
#if __has_builtin(__builtin_amdgcn_exp2f)
  return __builtin_amdgcn_exp2f(x);
#else
  return exp2f(x);
#endif
}

// ============================ k_prep: weight transposes + att-fold rows ============================
__global__ __launch_bounds__(256) void k_prep(const float* __restrict__ W1, const float* __restrict__ W2,
                                              const float* __restrict__ Wc,
                                              const float* __restrict__ as1, const float* __restrict__ ad1,
                                              const float* __restrict__ as2, const float* __restrict__ ad2,
                                              half_t* __restrict__ WT1, half_t* __restrict__ WT2,
                                              half_t* __restrict__ WTc) {
  __shared__ float tile[64][65];
  int b = blockIdx.x, t = threadIdx.x;
  if (b < 10) {
    const float* W; half_t* WT; int k0, n0, N, NTr;
    if (b < 4)      { W = W1; WT = WT1; k0 = (b >> 1) * 64; n0 = (b & 1) * 64; N = 128; NTr = 128; }
    else if (b < 8) { int bb = b - 4; W = W2; WT = WT2; k0 = (bb >> 1) * 64; n0 = (bb & 1) * 64; N = 128; NTr = 128; }
    else            { int bb = b - 8; W = Wc; WT = WTc; k0 = bb * 64; n0 = 0; N = 40; NTr = 48; }
    int col = t & 63, r4 = t >> 6;
#pragma unroll
    for (int i = 0; i < 16; i++) {
      int row = r4 * 16 + i;                       // k-local
      float v = 0.f;
      if (n0 + col < N) v = W[(size_t)(k0 + row) * N + n0 + col];
      tile[row][col] = v;
    }
    __syncthreads();
#pragma unroll
    for (int i = 0; i < 16; i++) {
      int nrow = r4 * 16 + i;                      // n-local
      if (n0 + nrow < NTr) WT[(size_t)(n0 + nrow) * 128 + k0 + col] = (half_t)tile[col][nrow];
    }
    return;
  }
  // fold rows: WT rows 128..135 = (W @ att per head) / ln2; rows 136..143 zero
  const float* W  = (b == 10) ? W1 : W2;
  const float* as = (b == 10) ? as1 : as2;
  const float* ad = (b == 10) ? ad1 : ad2;
  half_t* WT      = (b == 10) ? WT1 : WT2;
  int e = t >> 5, kr = t & 31, h = e & 3;
  const float* att = ((e < 4) ? as : ad) + h * 32;
#pragma unroll
  for (int u = 0; u < 4; u++) {
    int k = u * 32 + kr;
    const float* wrow = W + (size_t)k * 128 + h * 32;
    float s = 0.f;
#pragma unroll
    for (int c = 0; c < 32; c += 4) {
      float4 wv = *(const float4*)(wrow + c);
      float4 av = *(const float4*)(att + c);
      s += wv.x * av.x + wv.y * av.y + wv.z * av.z + wv.w * av.w;
    }
    WT[(size_t)(128 + e) * 128 + k] = (half_t)(s * RLN2);
  }
  for (int u = t; u < 8 * 128; u += 256) WT[(size_t)136 * 128 + u] = (half_t)0.f;
}

// ============================ k_binA: standalone edge binning (was k_front role) ==================
__global__ __launch_bounds__(256) void k_binA(const int* __restrict__ src, const int* __restrict__ dst,
                                              unsigned int* __restrict__ bpk, int* __restrict__ gcnt) {
  __shared__ int hist[NBK];
  __shared__ int hscan[NBK];
  __shared__ int cnt[NBK];
  __shared__ int ssc[256];
  __shared__ unsigned int staged[TA];
  int t = threadIdx.x;
  int hb = blockIdx.x;
  int e0 = hb * TA;
  if (t < NBK) { hist[t] = 0; cnt[t] = 0; }
  __syncthreads();
  for (int i = 0; i < TA / 256; i++) {
    int e = e0 + t + i * 256;
    if (e < NE) atomicAdd(&hist[dst[e] >> BSH], 1);
  }
  __syncthreads();
  // exclusive scan of hist (196 <= 256)
  {
    int v = (t < NBK) ? hist[t] : 0;
    int x = v;
    ssc[t] = x;
    for (int off = 1; off < 256; off <<= 1) {
      __syncthreads();
      int y = (t >= off) ? ssc[t - off] : 0;
      __syncthreads();
      x += y;
      ssc[t] = x;
    }
    if (t < NBK) hscan[t] = x - v;
  }
  __syncthreads();
  for (int i = 0; i < TA / 256; i++) {
    int e = e0 + t + i * 256;
    if (e < NE) {
      int d = dst[e];
      int bk = d >> BSH;
      int pos = hscan[bk] + atomicAdd(&cnt[bk], 1);
      staged[pos] = ((unsigned int)src[e] << BSH) | (unsigned int)(d & (BSZ - 1));
    }
  }
  __syncthreads();
  // concurrent cursor reservation: 196 independent atomics, one round-trip
  if (t < NBK) {
    int c = hist[t];
    cnt[t] = (c > 0) ? atomicAdd(&gcnt[t], c) : 0;
  }
  __syncthreads();
  // atomic-free flush into contiguous per-bucket region
  int wave = t >> 6, lane = t & 63;
  for (int bk = wave; bk < NBK; bk += 4) {
    int c = hist[bk];
    int lo = hscan[bk];
    int base = cnt[bk];
    int avail = CAP2R - base;
    int cw = min(c, max(avail, 0));
    size_t bb = (size_t)bk * CAP2R + base;
    for (int j = lane; j < cw; j += 64) bpk[bb + j] = staged[lo + j];
  }
}

// ============================ k_gemm1: standalone (was k_front role; barrier-free k-loop) =========
__global__ __launch_bounds__(256) void k_gemm1(const float* __restrict__ X, const half_t* __restrict__ WT1,
                                               half_t* __restrict__ H, float* __restrict__ asrc,
                                               float* __restrict__ adst) {
  __shared__ __align__(16) half_t Wt[144 * WPAD];
  int t = threadIdx.x;
  int wave = t >> 6, lane = t & 63;
  int l15 = lane & 15, quad = lane >> 4;
  int rb = blockIdx.x * 128;

  for (int c = t; c < 2304; c += 256) {          // 144*128/8 chunks
    int row = c >> 4;
    int c8 = (c & 15) * 8;
    *(f16x8*)(Wt + row * WPAD + c8) = *(const f16x8*)(WT1 + (size_t)row * 128 + c8);
  }
  __syncthreads();

  int rowA0 = rb + wave * 32 + l15;
  int rowA1 = rowA0 + 16;
  bool v0 = rowA0 < NN, v1 = rowA1 < NN;
  const float* xp0 = X + (size_t)rowA0 * 128 + quad * 8;
  const float* xp1 = X + (size_t)rowA1 * 128 + quad * 8;

  f32x4 acc[2][9];
#pragma unroll
  for (int rt = 0; rt < 2; rt++)
#pragma unroll
    for (int ct = 0; ct < 9; ct++) acc[rt][ct] = (f32x4){0.f, 0.f, 0.f, 0.f};

#pragma unroll
  for (int kk = 0; kk < 4; kk++) {
    int k0 = kk * 32;
    f16x8 a0 = (f16x8)(half_t)0, a1 = (f16x8)(half_t)0;
    if (v0) {
      float4 p = *(const float4*)(xp0 + k0);
      float4 q = *(const float4*)(xp0 + k0 + 4);
      a0[0] = (half_t)p.x; a0[1] = (half_t)p.y; a0[2] = (half_t)p.z; a0[3] = (half_t)p.w;
      a0[4] = (half_t)q.x; a0[5] = (half_t)q.y; a0[6] = (half_t)q.z; a0[7] = (half_t)q.w;
    }
    if (v1) {
      float4 p = *(const float4*)(xp1 + k0);
      float4 q = *(const float4*)(xp1 + k0 + 4);
      a1[0] = (half_t)p.x; a1[1] = (half_t)p.y; a1[2] = (half_t)p.z; a1[3] = (half_t)p.w;
      a1[4] = (half_t)q.x; a1[5] = (half_t)q.y; a1[6] = (half_t)q.z; a1[7] = (half_t)q.w;
    }
#pragma unroll
    for (int ct = 0; ct < 9; ct++) {
      f16x8 b = *(const f16x8*)(Wt + (ct * 16 + l15) * WPAD + k0 + quad * 8);
      acc[0][ct] = __builtin_amdgcn_mfma_f32_16x16x32_f16(a0, b, acc[0][ct], 0, 0, 0);
      acc[1][ct] = __builtin_amdgcn_mfma_f32_16x16x32_f16(a1, b, acc[1][ct], 0, 0, 0);
    }
  }

#pragma unroll
  for (int rt = 0; rt < 2; rt++) {
    int rbase = rb + wave * 32 + rt * 16 + quad * 4;
#pragma unroll
    for (int reg = 0; reg < 4; reg++) {
      int row = rbase + reg;
      if (row < NN) {
#pragma unroll
        for (int ct = 0; ct < 8; ct++) {
          H[(size_t)row * 128 + ct * 16 + l15] = (half_t)acc[rt][ct][reg];
        }
        if (l15 < 8) {
          float v = acc[rt][8][reg];
          if (l15 < 4) asrc[row * 4 + l15] = v;
          else         adst[row * 4 + (l15 - 4)] = v;
        }
      }
    }
  }
}

// ============================ binB (byte-identical r10) ============================
__global__ __launch_bounds__(512) void k_binB(const unsigned int* __restrict__ bpk,
                                              const int* __restrict__ gcnt,
                                              int* __restrict__ sbeg, int* __restrict__ send,
                                              int* __restrict__ adj) {
  __shared__ int lhist[BSZ];
  __shared__ int lscan[BSZ];
  __shared__ int lcur[BSZ];
  __shared__ int ssc[512];
  __shared__ unsigned int staged[CAP2];
  int b = blockIdx.x;
  int t = threadIdx.x;
  int nbeg = b << BSH;
  int nloc = min(BSZ, NN - nbeg);
  int adjb = b * CAP2;
  int cr = min(gcnt[b], CAP2R);
  size_t rbase = (size_t)b * CAP2R;
  lhist[t] = (t < nloc) ? 1 : 0;           // self-loop in slot 0 of each node's segment
  lcur[t] = 1;
  __syncthreads();
  for (int j = t; j < cr; j += 512) atomicAdd(&lhist[bpk[rbase + j] & (BSZ - 1)], 1);
  __syncthreads();
  {
    int v = lhist[t];
    int x = v;
    ssc[t] = x;
    for (int off = 1; off < 512; off <<= 1) {
      __syncthreads();
      int y = (t >= off) ? ssc[t - off] : 0;
      __syncthreads();
      x += y;
      ssc[t] = x;
    }
    lscan[t] = x - v;
  }
  __syncthreads();
  int total = lscan[BSZ - 1] + lhist[BSZ - 1];
  if (t < nloc) {
    int bg = adjb + lscan[t];
    sbeg[nbeg + t] = bg;
    send[nbeg + t] = bg + lhist[t];
    staged[lscan[t]] = (unsigned int)(nbeg + t);
  }
  __syncthreads();
  for (int j = t; j < cr; j += 512) {
    unsigned int v = bpk[rbase + j];
    int dl = v & (BSZ - 1);
    int idx = lscan[dl] + atomicAdd(&lcur[dl], 1);
    if (idx < CAP2) staged[idx] = v >> BSH;
  }
  __syncthreads();
  int lim = min(total, CAP2);
  for (int i = t; i < lim; i += 512) adj[adjb + i] = (int)staged[i];
}

// ============================ aggregation (r7 shuffle version — best measured) ============
__global__ __launch_bounds__(256) void k_agg(const half_t* __restrict__ H, const int* __restrict__ sbeg,
                                             const int* __restrict__ send, const int* __restrict__ adj,
                                             const float* __restrict__ asrc, const float* __restrict__ adst,
                                             const float* __restrict__ bias, half_t* __restrict__ out) {
  int n = blockIdx.x * 4 + (threadIdx.x >> 6);
  if (n >= NN) return;
  int lane = threadIdx.x & 63;
  int sub = lane & 7;              // 16-channel slice [sub*16, sub*16+16)
  int g = lane >> 3;               // edge group [0,8)
  int head = sub >> 1;
  float ad = adst[(size_t)n * 4 + head];
  float acc[16];
#pragma unroll
  for (int j = 0; j < 16; j++) acc[j] = 0.f;
  float wsum = 0.f;
  int beg = sbeg[n], end = send[n];
  int i = beg + g;
  int s = 0;
  float a = 0.f;
  f16x8 h0 = (f16x8)(half_t)0, h1 = (f16x8)(half_t)0;
  if (i < end) {
    s = adj[i];
    a = asrc[(size_t)s * 4 + head];
    const f16x8* hp = (const f16x8*)(H + (size_t)s * 128 + sub * 16);
    h0 = hp[0]; h1 = hp[1];
  }
  while (i < end) {
    int inext = i + 8;
    int sn = 0;
    float an = 0.f;
    if (inext < end) {             // prefetch next edge's index + logit
      sn = adj[inext];
      an = asrc[(size_t)sn * 4 + head];
    }
    const f16x8* hpn = (const f16x8*)(H + (size_t)sn * 128 + sub * 16);
    f16x8 g0 = hpn[0], g1 = hpn[1];
    float ev = a + ad;
    ev = (ev > 0.f) ? ev : 0.2f * ev;
    float w = fast_exp2(ev);
    wsum += w;
#pragma unroll
    for (int j = 0; j < 8; j++) acc[j] += w * (float)h0[j];
#pragma unroll
    for (int j = 0; j < 8; j++) acc[8 + j] += w * (float)h1[j];
    s = sn; a = an; h0 = g0; h1 = g1; i = inext;
  }
#pragma unroll
  for (int m = 8; m < 64; m <<= 1) {
    wsum += __shfl_xor(wsum, m, 64);
#pragma unroll
    for (int j = 0; j < 16; j++) acc[j] += __shfl_xor(acc[j], m, 64);
  }
  float scale = 1.0f / (wsum + 1e-16f);
  float o0 = acc[0], o1 = acc[1];
#pragma unroll
  for (int r = 1; r < 8; r++) {
    if (g == r) { o0 = acc[2 * r]; o1 = acc[2 * r + 1]; }
  }
  int ch = sub * 16 + g * 2;
  o0 = fmaxf(o0 * scale + bias[ch], 0.f);
  o1 = fmaxf(o1 * scale + bias[ch + 1], 0.f);
  f16x2 o;
  o[0] = (half_t)o0;
  o[1] = (half_t)o1;
  *(f16x2*)(out + (size_t)n * 128 + ch) = o;
}

// ============================ MFMA GEMM: Wt staged once, barrier-free k-loop (byte-identical r10) =
__global__ __launch_bounds__(256) void k_gemm_att(const half_t* __restrict__ X, const half_t* __restrict__ WT,
                                                  half_t* __restrict__ H, float* __restrict__ asrc,
                                                  float* __restrict__ adst) {
  __shared__ __align__(16) half_t Wt[144 * WPAD];
  int t = threadIdx.x;
  int wave = t >> 6, lane = t & 63;
  int l15 = lane & 15, quad = lane >> 4;
  int rb = blockIdx.x * 64;

  for (int c = t; c < 2304; c += 256) {          // 144*128/8 chunks
    int row = c >> 4;
    int c8 = (c & 15) * 8;
    *(f16x8*)(Wt + row * WPAD + c8) = *(const f16x8*)(WT + (size_t)row * 128 + c8);
  }
  __syncthreads();

  int rowA = rb + wave * 16 + l15;
  bool va = rowA < NN;
  const half_t* xp = X + (size_t)rowA * 128 + quad * 8;

  f32x4 acc[9];
#pragma unroll
  for (int ct = 0; ct < 9; ct++) acc[ct] = (f32x4){0.f, 0.f, 0.f, 0.f};

#pragma unroll
  for (int kk = 0; kk < 4; kk++) {
    int k0 = kk * 32;
    f16x8 a0 = (f16x8)(half_t)0;
    if (va) a0 = *(const f16x8*)(xp + k0);
#pragma unroll
    for (int ct = 0; ct < 9; ct++) {
      f16x8 b = *(const f16x8*)(Wt + (ct * 16 + l15) * WPAD + k0 + quad * 8);
      acc[ct] = __builtin_amdgcn_mfma_f32_16x16x32_f16(a0, b, acc[ct], 0, 0, 0);
    }
  }

  int rbase = rb + wave * 16 + quad * 4;
#pragma unroll
  for (int reg = 0; reg < 4; reg++) {
    int row = rbase + reg;
    if (row < NN) {
#pragma unroll
      for (int ct = 0; ct < 8; ct++) {
        H[(size_t)row * 128 + ct * 16 + l15] = (half_t)acc[ct][reg];
      }
      if (l15 < 8) {
        float v = acc[8][reg];
        if (l15 < 4) asrc[row * 4 + l15] = v;
        else         adst[row * 4 + (l15 - 4)] = v;
      }
    }
  }
}

// ============================ classifier (byte-identical r10) ========
__global__ __launch_bounds__(256) void k_classifier(const half_t* __restrict__ Hf, const half_t* __restrict__ WTc,
                                                    const float* __restrict__ bc, float* __restrict__ out) {
  __shared__ __align__(16) half_t Wt[48 * WPAD];
  int t = threadIdx.x;
  int wave = t >> 6, lane = t & 63;
  int l15 = lane & 15, quad = lane >> 4;
  int rb = blockIdx.x * 64;

  for (int c = t; c < 768; c += 256) {           // 48*128/8 chunks
    int row = c >> 4;
    int c8 = (c & 15) * 8;
    *(f16x8*)(Wt + row * WPAD + c8) = *(const f16x8*)(WTc + (size_t)row * 128 + c8);
  }
  __syncthreads();

  int rowA = rb + wave * 16 + l15;
  bool va = rowA < NN;
  const half_t* xp = Hf + (size_t)rowA * 128 + quad * 8;

  f32x4 acc[3];
#pragma unroll
  for (int ct = 0; ct < 3; ct++) acc[ct] = (f32x4){0.f, 0.f, 0.f, 0.f};

#pragma unroll
  for (int kk = 0; kk < 4; kk++) {
    int k0 = kk * 32;
    f16x8 a0 = (f16x8)(half_t)0;
    if (va) a0 = *(const f16x8*)(xp + k0);
#pragma unroll
    for (int ct = 0; ct < 3; ct++) {
      f16x8 b = *(const f16x8*)(Wt + (ct * 16 + l15) * WPAD + k0 + quad * 8);
      acc[ct] = __builtin_amdgcn_mfma_f32_16x16x32_f16(a0, b, acc[ct], 0, 0, 0);
    }
  }

#pragma unroll
  for (int ct = 0; ct < 3; ct++) {
    int col = ct * 16 + l15;
    if (col < 40) {
      float bv = bc[col];
#pragma unroll
      for (int reg = 0; reg < 4; reg++) {
        int row = rb + wave * 16 + quad * 4 + reg;
        if (row < NN) out[(size_t)row * 40 + col] = acc[ct][reg] + bv;
      }
    }
  }
}

// ============================ launch ============================

extern "C" void kernel_launch(void* const* d_in, const int* in_sizes, int n_in,
                              void* d_out, int out_size, void* d_ws, size_t ws_size,
                              hipStream_t stream) {
  const float* x   = (const float*)d_in[0];
  const int*   ei  = (const int*)d_in[1];
  const float* W1  = (const float*)d_in[2];
  const float* as1 = (const float*)d_in[3];
  const float* ad1 = (const float*)d_in[4];
  const float* b1  = (const float*)d_in[5];
  const float* W2  = (const float*)d_in[6];
  const float* as2 = (const float*)d_in[7];
  const float* ad2 = (const float*)d_in[8];
  const float* b2  = (const float*)d_in[9];
  const float* Wc  = (const float*)d_in[10];
  const float* bc  = (const float*)d_in[11];
  float* out = (float*)d_out;

  const int* esrc = ei;
  const int* edst = ei + NE;

  char* w = (char*)d_ws;
  auto alloc = [&](size_t bytes) {
    void* p = (void*)w;
    w += (bytes + 255) & ~(size_t)255;
    return p;
  };
  half_t* A   = (half_t*)alloc(sizeof(half_t) * (size_t)NN * 128);  // gather target
  half_t* B   = (half_t*)alloc(sizeof(half_t) * (size_t)NN * 128);  // layer output
  float* asrc = (float*)alloc(sizeof(float) * (size_t)NN * 4);
  float* adst = (float*)alloc(sizeof(float) * (size_t)NN * 4);
  int* sbeg   = (int*)alloc(sizeof(int) * NN);
  int* send   = (int*)alloc(sizeof(int) * NN);
  unsigned int* bpk = (unsigned int*)alloc(sizeof(unsigned int) * (size_t)NBK * CAP2R);
  int* gcnt   = (int*)alloc(sizeof(int) * NBK);
  int* adj    = (int*)alloc(sizeof(int) * (size_t)NBK * CAP2);
  half_t* WT1 = (half_t*)alloc(sizeof(half_t) * 144 * 128);
  half_t* WT2 = (half_t*)alloc(sizeof(half_t) * 144 * 128);
  half_t* WTc = (half_t*)alloc(sizeof(half_t) * 48 * 128);

  // ---- zero per-bucket cursors ----
  hipMemsetAsync(gcnt, 0, sizeof(int) * NBK, stream);

  // ---- weight prep (WT1/WT2 fold rows pre-scaled by 1/ln2; WTc) ----
  k_prep<<<12, 256, 0, stream>>>(W1, W2, Wc, as1, ad1, as2, ad2, WT1, WT2, WTc);

  // ---- edge binning (now standalone for per-kernel profiling) ----
  k_binA<<<NBA, 256, 0, stream>>>(esrc, edst, bpk, gcnt);

  // ---- gemm1 (standalone) ----
  k_gemm1<<<NBG, 256, 0, stream>>>(x, WT1, A, asrc, adst);

  // ---- CSR finalize ----
  k_binB<<<NBK, 512, 0, stream>>>(bpk, gcnt, sbeg, send, adj);

  // ---- layer 1 aggregate ----
  k_agg<<<(NN + 3) / 4, 256, 0, stream>>>(A, sbeg, send, adj, asrc, adst, b1, B);

  // ---- layer 2 ----
  k_gemm_att<<<(NN + 63) / 64, 256, 0, stream>>>(B, WT2, A, asrc, adst);
  k_agg<<<(NN + 3) / 4, 256, 0, stream>>>(A, sbeg, send, adj, asrc, adst, b2, B);

  // ---- classifier ----
  k_classifier<<<(NN + 63) / 64, 256, 0, stream>>>(B, WTc, bc, out);
}

// Round 13
// 346.943 us; speedup vs baseline: 1.0441x; 1.0441x over previous
//
#include <hip/hip_runtime.h>

#define NN    100000
#define NE    1600000
#define BSH   9            // 512 nodes per bucket
#define BSZ   512
#define NBK   196          // ceil(NN/512)
#define TA    8192         // edges per binA chunk-block
#define NBA   196          // ceil(NE/TA)
#define CAP2R 8960         // per-bucket raw edge capacity (mean 8163, +8.8 sigma)
#define CAP2  9472         // per-bucket capacity incl. self-loops (CAP2R + 512)
#define NBG   782          // gemm1 blocks
#define WPAD  136          // Wt LDS row pitch (halves): 272B -> bank stride 4, 2-way max
#define RLN2  1.4426950408889634f

typedef _Float16 half_t;
typedef __attribute__((ext_vector_type(2))) _Float16 f16x2;
typedef __attribute__((ext_vector_type(4))) _Float16 f16x4;
typedef __attribute__((ext_vector_type(8))) _Float16 f16x8;
typedef __attribute__((ext_vector_type(4))) float    f32x4;

__device__ inline float fast_exp2(float x) {
#if __has_builtin(__builtin_amdgcn_exp2f)
  return __builtin_amdgcn_exp2f(x);
#else
  return exp2f(x);
#endif
}

// ============================ k1: binA (blocks 0..195) ∥ weight-prep (blocks 196..207) ============
__global__ __launch_bounds__(256) void k1_bin_prep(const int* __restrict__ src, const int* __restrict__ dst,
                                                   unsigned int* __restrict__ bpk, int* __restrict__ gcnt,
                                                   const float* __restrict__ W1, const float* __restrict__ W2,
                                                   const float* __restrict__ Wc,
                                                   const float* __restrict__ as1, const float* __restrict__ ad1,
                                                   const float* __restrict__ as2, const float* __restrict__ ad2,
                                                   half_t* __restrict__ WT1, half_t* __restrict__ WT2,
                                                   half_t* __restrict__ WTc) {
  __shared__ __align__(16) char smem[36864];
  int t = threadIdx.x;
  int bid = blockIdx.x;

  if (bid < NBA) {
    // ---- binA role (r12-proven) ----
    int hb = bid;
    int* hist  = (int*)smem;                  // [196]
    int* hscan = hist + NBK;                  // [196]
    int* cnt   = hscan + NBK;                 // [196] scatter cursor; reused as gbase
    int* ssc   = cnt + NBK;                   // [256]
    unsigned int* staged = (unsigned int*)(ssc + 256);  // [8192]
    int e0 = hb * TA;
    if (t < NBK) { hist[t] = 0; cnt[t] = 0; }
    __syncthreads();
    for (int i = 0; i < TA / 256; i++) {
      int e = e0 + t + i * 256;
      if (e < NE) atomicAdd(&hist[dst[e] >> BSH], 1);
    }
    __syncthreads();
    // exclusive scan of hist (196 <= 256)
    {
      int v = (t < NBK) ? hist[t] : 0;
      int x = v;
      ssc[t] = x;
      for (int off = 1; off < 256; off <<= 1) {
        __syncthreads();
        int y = (t >= off) ? ssc[t - off] : 0;
        __syncthreads();
        x += y;
        ssc[t] = x;
      }
      if (t < NBK) hscan[t] = x - v;
    }
    __syncthreads();
    for (int i = 0; i < TA / 256; i++) {
      int e = e0 + t + i * 256;
      if (e < NE) {
        int d = dst[e];
        int bk = d >> BSH;
        int pos = hscan[bk] + atomicAdd(&cnt[bk], 1);
        staged[pos] = ((unsigned int)src[e] << BSH) | (unsigned int)(d & (BSZ - 1));
      }
    }
    __syncthreads();
    // concurrent cursor reservation: 196 independent atomics, one round-trip
    if (t < NBK) {
      int c = hist[t];
      cnt[t] = (c > 0) ? atomicAdd(&gcnt[t], c) : 0;
    }
    __syncthreads();
    // atomic-free flush into contiguous per-bucket region
    int wave = t >> 6, lane = t & 63;
    for (int bk = wave; bk < NBK; bk += 4) {
      int c = hist[bk];
      int lo = hscan[bk];
      int base = cnt[bk];
      int avail = CAP2R - base;
      int cw = min(c, max(avail, 0));
      size_t bb = (size_t)bk * CAP2R + base;
      for (int j = lane; j < cw; j += 64) bpk[bb + j] = staged[lo + j];
    }
    return;
  }

  // ---- weight-prep role (r12-proven) ----
  int b = bid - NBA;
  if (b < 10) {
    float (*tile)[65] = (float(*)[65])smem;   // 64x65 fp32 = 16.6KB
    const float* W; half_t* WT; int k0, n0, N, NTr;
    if (b < 4)      { W = W1; WT = WT1; k0 = (b >> 1) * 64; n0 = (b & 1) * 64; N = 128; NTr = 128; }
    else if (b < 8) { int bb = b - 4; W = W2; WT = WT2; k0 = (bb >> 1) * 64; n0 = (bb & 1) * 64; N = 128; NTr = 128; }
    else            { int bb = b - 8; W = Wc; WT = WTc; k0 = bb * 64; n0 = 0; N = 40; NTr = 48; }
    int col = t & 63, r4 = t >> 6;
#pragma unroll
    for (int i = 0; i < 16; i++) {
      int row = r4 * 16 + i;                       // k-local
      float v = 0.f;
      if (n0 + col < N) v = W[(size_t)(k0 + row) * N + n0 + col];
      tile[row][col] = v;
    }
    __syncthreads();
#pragma unroll
    for (int i = 0; i < 16; i++) {
      int nrow = r4 * 16 + i;                      // n-local
      if (n0 + nrow < NTr) WT[(size_t)(n0 + nrow) * 128 + k0 + col] = (half_t)tile[col][nrow];
    }
    return;
  }
  // fold rows: WT rows 128..135 = (W @ att per head) / ln2; rows 136..143 zero
  const float* W  = (b == 10) ? W1 : W2;
  const float* as = (b == 10) ? as1 : as2;
  const float* ad = (b == 10) ? ad1 : ad2;
  half_t* WT      = (b == 10) ? WT1 : WT2;
  int e = t >> 5, kr = t & 31, h = e & 3;
  const float* att = ((e < 4) ? as : ad) + h * 32;
#pragma unroll
  for (int u = 0; u < 4; u++) {
    int k = u * 32 + kr;
    const float* wrow = W + (size_t)k * 128 + h * 32;
    float s = 0.f;
#pragma unroll
    for (int c = 0; c < 32; c += 4) {
      float4 wv = *(const float4*)(wrow + c);
      float4 av = *(const float4*)(att + c);
      s += wv.x * av.x + wv.y * av.y + wv.z * av.z + wv.w * av.w;
    }
    WT[(size_t)(128 + e) * 128 + k] = (half_t)(s * RLN2);
  }
  for (int u = t; u < 8 * 128; u += 256) WT[(size_t)136 * 128 + u] = (half_t)0.f;
}

// ============================ k2: binB (blocks 0..195, 256-thr r1 scan) ∥ gemm1 (196..977) ========
__global__ __launch_bounds__(256) void k2_csr_gemm1(const unsigned int* __restrict__ bpk,
                                                    const int* __restrict__ gcnt,
                                                    int* __restrict__ sbeg, int* __restrict__ send,
                                                    int* __restrict__ adj,
                                                    const float* __restrict__ X, const half_t* __restrict__ WT1,
                                                    half_t* __restrict__ H, float* __restrict__ asrc,
                                                    float* __restrict__ adst) {
  __shared__ __align__(16) char smem[45056];
  int t = threadIdx.x;
  int bid = blockIdx.x;

  if (bid < NBK) {
    // ---- binB role: contiguous reads + r1's 256-thread 2-elem scan ----
    int* lhist = (int*)smem;                        // [512]
    int* lscan = lhist + BSZ;                       // [512]
    int* lcur  = lscan + BSZ;                       // [512]
    int* ssc   = lcur + BSZ;                        // [256]
    unsigned int* staged = (unsigned int*)(ssc + 256);  // [9472]
    int b = bid;
    int nbeg = b << BSH;
    int nloc = min(BSZ, NN - nbeg);
    int adjb = b * CAP2;
    int cr = min(gcnt[b], CAP2R);
    size_t rbase = (size_t)b * CAP2R;
    lhist[2 * t] = (2 * t < nloc) ? 1 : 0;          // self-loop in slot 0 of each node's segment
    lhist[2 * t + 1] = (2 * t + 1 < nloc) ? 1 : 0;
    lcur[2 * t] = 1;
    lcur[2 * t + 1] = 1;
    __syncthreads();
    // pass 1: histogram by local dst
    for (int j = t; j < cr; j += 256) atomicAdd(&lhist[bpk[rbase + j] & (BSZ - 1)], 1);
    __syncthreads();
    // exclusive scan of 512 with 256 threads (r1-proven)
    {
      int v0 = lhist[2 * t], v1 = lhist[2 * t + 1];
      int s2 = v0 + v1;
      int x = s2;
      ssc[t] = x;
      for (int off = 1; off < 256; off <<= 1) {
        __syncthreads();
        int y = (t >= off) ? ssc[t - off] : 0;
        __syncthreads();
        x += y;
        ssc[t] = x;
      }
      int ex = x - s2;
      lscan[2 * t] = ex;
      lscan[2 * t + 1] = ex + v0;
    }
    __syncthreads();
    int total = lscan[BSZ - 1] + lhist[BSZ - 1];
    // per-node CSR bounds + self-loop records
#pragma unroll
    for (int u = 0; u < 2; u++) {
      int i2 = t + u * 256;
      if (i2 < nloc) {
        int bg = adjb + lscan[i2];
        sbeg[nbeg + i2] = bg;
        send[nbeg + i2] = bg + lhist[i2];
        staged[lscan[i2]] = (unsigned int)(nbeg + i2);
      }
    }
    __syncthreads();
    // pass 2: scatter edges into sorted staging (slots after the self-loop)
    for (int j = t; j < cr; j += 256) {
      unsigned int v = bpk[rbase + j];
      int dl = v & (BSZ - 1);
      int idx = lscan[dl] + atomicAdd(&lcur[dl], 1);
      if (idx < CAP2) staged[idx] = v >> BSH;
    }
    __syncthreads();
    // contiguous stream-out
    int lim = min(total, CAP2);
    for (int i2 = t; i2 < lim; i2 += 256) adj[adjb + i2] = (int)staged[i2];
    return;
  }

  // ---- gemm1 role (r12-proven): stage full WT1 once, barrier-free k-loop ----
  half_t* Wt = (half_t*)smem;          // [144][WPAD] = 39168 B
  int wave = t >> 6, lane = t & 63;
  int l15 = lane & 15, quad = lane >> 4;
  int rb = (bid - NBK) * 128;

  for (int c = t; c < 2304; c += 256) {          // 144*128/8 chunks
    int row = c >> 4;
    int c8 = (c & 15) * 8;
    *(f16x8*)(Wt + row * WPAD + c8) = *(const f16x8*)(WT1 + (size_t)row * 128 + c8);
  }
  __syncthreads();

  int rowA0 = rb + wave * 32 + l15;
  int rowA1 = rowA0 + 16;
  bool v0 = rowA0 < NN, v1 = rowA1 < NN;
  const float* xp0 = X + (size_t)rowA0 * 128 + quad * 8;
  const float* xp1 = X + (size_t)rowA1 * 128 + quad * 8;

  f32x4 acc[2][9];
#pragma unroll
  for (int rt = 0; rt < 2; rt++)
#pragma unroll
    for (int ct = 0; ct < 9; ct++) acc[rt][ct] = (f32x4){0.f, 0.f, 0.f, 0.f};

#pragma unroll
  for (int kk = 0; kk < 4; kk++) {
    int k0 = kk * 32;
    f16x8 a0 = (f16x8)(half_t)0, a1 = (f16x8)(half_t)0;
    if (v0) {
      float4 p = *(const float4*)(xp0 + k0);
      float4 q = *(const float4*)(xp0 + k0 + 4);
      a0[0] = (half_t)p.x; a0[1] = (half_t)p.y; a0[2] = (half_t)p.z; a0[3] = (half_t)p.w;
      a0[4] = (half_t)q.x; a0[5] = (half_t)q.y; a0[6] = (half_t)q.z; a0[7] = (half_t)q.w;
    }
    if (v1) {
      float4 p = *(const float4*)(xp1 + k0);
      float4 q = *(const float4*)(xp1 + k0 + 4);
      a1[0] = (half_t)p.x; a1[1] = (half_t)p.y; a1[2] = (half_t)p.z; a1[3] = (half_t)p.w;
      a1[4] = (half_t)q.x; a1[5] = (half_t)q.y; a1[6] = (half_t)q.z; a1[7] = (half_t)q.w;
    }
#pragma unroll
    for (int ct = 0; ct < 9; ct++) {
      f16x8 b = *(const f16x8*)(Wt + (ct * 16 + l15) * WPAD + k0 + quad * 8);
      acc[0][ct] = __builtin_amdgcn_mfma_f32_16x16x32_f16(a0, b, acc[0][ct], 0, 0, 0);
      acc[1][ct] = __builtin_amdgcn_mfma_f32_16x16x32_f16(a1, b, acc[1][ct], 0, 0, 0);
    }
  }

#pragma unroll
  for (int rt = 0; rt < 2; rt++) {
    int rbase = rb + wave * 32 + rt * 16 + quad * 4;
#pragma unroll
    for (int reg = 0; reg < 4; reg++) {
      int row = rbase + reg;
      if (row < NN) {
#pragma unroll
        for (int ct = 0; ct < 8; ct++) {
          H[(size_t)row * 128 + ct * 16 + l15] = (half_t)acc[rt][ct][reg];
        }
        if (l15 < 8) {
          float v = acc[rt][8][reg];
          if (l15 < 4) asrc[row * 4 + l15] = v;
          else         adst[row * 4 + (l15 - 4)] = v;
        }
      }
    }
  }
}

// ============================ aggregation (r7 shuffle version — best measured) ============
__global__ __launch_bounds__(256) void k_agg(const half_t* __restrict__ H, const int* __restrict__ sbeg,
                                             const int* __restrict__ send, const int* __restrict__ adj,
                                             const float* __restrict__ asrc, const float* __restrict__ adst,
                                             const float* __restrict__ bias, half_t* __restrict__ out) {
  int n = blockIdx.x * 4 + (threadIdx.x >> 6);
  if (n >= NN) return;
  int lane = threadIdx.x & 63;
  int sub = lane & 7;              // 16-channel slice [sub*16, sub*16+16)
  int g = lane >> 3;               // edge group [0,8)
  int head = sub >> 1;
  float ad = adst[(size_t)n * 4 + head];
  float acc[16];
#pragma unroll
  for (int j = 0; j < 16; j++) acc[j] = 0.f;
  float wsum = 0.f;
  int beg = sbeg[n], end = send[n];
  int i = beg + g;
  int s = 0;
  float a = 0.f;
  f16x8 h0 = (f16x8)(half_t)0, h1 = (f16x8)(half_t)0;
  if (i < end) {
    s = adj[i];
    a = asrc[(size_t)s * 4 + head];
    const f16x8* hp = (const f16x8*)(H + (size_t)s * 128 + sub * 16);
    h0 = hp[0]; h1 = hp[1];
  }
  while (i < end) {
    int inext = i + 8;
    int sn = 0;
    float an = 0.f;
    if (inext < end) {             // prefetch next edge's index + logit
      sn = adj[inext];
      an = asrc[(size_t)sn * 4 + head];
    }
    const f16x8* hpn = (const f16x8*)(H + (size_t)sn * 128 + sub * 16);
    f16x8 g0 = hpn[0], g1 = hpn[1];
    float ev = a + ad;
    ev = (ev > 0.f) ? ev : 0.2f * ev;
    float w = fast_exp2(ev);
    wsum += w;
#pragma unroll
    for (int j = 0; j < 8; j++) acc[j] += w * (float)h0[j];
#pragma unroll
    for (int j = 0; j < 8; j++) acc[8 + j] += w * (float)h1[j];
    s = sn; a = an; h0 = g0; h1 = g1; i = inext;
  }
#pragma unroll
  for (int m = 8; m < 64; m <<= 1) {
    wsum += __shfl_xor(wsum, m, 64);
#pragma unroll
    for (int j = 0; j < 16; j++) acc[j] += __shfl_xor(acc[j], m, 64);
  }
  float scale = 1.0f / (wsum + 1e-16f);
  float o0 = acc[0], o1 = acc[1];
#pragma unroll
  for (int r = 1; r < 8; r++) {
    if (g == r) { o0 = acc[2 * r]; o1 = acc[2 * r + 1]; }
  }
  int ch = sub * 16 + g * 2;
  o0 = fmaxf(o0 * scale + bias[ch], 0.f);
  o1 = fmaxf(o1 * scale + bias[ch + 1], 0.f);
  f16x2 o;
  o[0] = (half_t)o0;
  o[1] = (half_t)o1;
  *(f16x2*)(out + (size_t)n * 128 + ch) = o;
}

// ============================ MFMA GEMM: Wt staged once, barrier-free k-loop (r10-proven) =========
__global__ __launch_bounds__(256) void k_gemm_att(const half_t* __restrict__ X, const half_t* __restrict__ WT,
                                                  half_t* __restrict__ H, float* __restrict__ asrc,
                                                  float* __restrict__ adst) {
  __shared__ __align__(16) half_t Wt[144 * WPAD];
  int t = threadIdx.x;
  int wave = t >> 6, lane = t & 63;
  int l15 = lane & 15, quad = lane >> 4;
  int rb = blockIdx.x * 64;

  for (int c = t; c < 2304; c += 256) {          // 144*128/8 chunks
    int row = c >> 4;
    int c8 = (c & 15) * 8;
    *(f16x8*)(Wt + row * WPAD + c8) = *(const f16x8*)(WT + (size_t)row * 128 + c8);
  }
  __syncthreads();

  int rowA = rb + wave * 16 + l15;
  bool va = rowA < NN;
  const half_t* xp = X + (size_t)rowA * 128 + quad * 8;

  f32x4 acc[9];
#pragma unroll
  for (int ct = 0; ct < 9; ct++) acc[ct] = (f32x4){0.f, 0.f, 0.f, 0.f};

#pragma unroll
  for (int kk = 0; kk < 4; kk++) {
    int k0 = kk * 32;
    f16x8 a0 = (f16x8)(half_t)0;
    if (va) a0 = *(const f16x8*)(xp + k0);
#pragma unroll
    for (int ct = 0; ct < 9; ct++) {
      f16x8 b = *(const f16x8*)(Wt + (ct * 16 + l15) * WPAD + k0 + quad * 8);
      acc[ct] = __builtin_amdgcn_mfma_f32_16x16x32_f16(a0, b, acc[ct], 0, 0, 0);
    }
  }

  int rbase = rb + wave * 16 + quad * 4;
#pragma unroll
  for (int reg = 0; reg < 4; reg++) {
    int row = rbase + reg;
    if (row < NN) {
#pragma unroll
      for (int ct = 0; ct < 8; ct++) {
        H[(size_t)row * 128 + ct * 16 + l15] = (half_t)acc[ct][reg];
      }
      if (l15 < 8) {
        float v = acc[8][reg];
        if (l15 < 4) asrc[row * 4 + l15] = v;
        else         adst[row * 4 + (l15 - 4)] = v;
      }
    }
  }
}

// ============================ classifier (r10-proven) ========
__global__ __launch_bounds__(256) void k_classifier(const half_t* __restrict__ Hf, const half_t* __restrict__ WTc,
                                                    const float* __restrict__ bc, float* __restrict__ out) {
  __shared__ __align__(16) half_t Wt[48 * WPAD];
  int t = threadIdx.x;
  int wave = t >> 6, lane = t & 63;
  int l15 = lane & 15, quad = lane >> 4;
  int rb = blockIdx.x * 64;

  for (int c = t; c < 768; c += 256) {           // 48*128/8 chunks
    int row = c >> 4;
    int c8 = (c & 15) * 8;
    *(f16x8*)(Wt + row * WPAD + c8) = *(const f16x8*)(WTc + (size_t)row * 128 + c8);
  }
  __syncthreads();

  int rowA = rb + wave * 16 + l15;
  bool va = rowA < NN;
  const half_t* xp = Hf + (size_t)rowA * 128 + quad * 8;

  f32x4 acc[3];
#pragma unroll
  for (int ct = 0; ct < 3; ct++) acc[ct] = (f32x4){0.f, 0.f, 0.f, 0.f};

#pragma unroll
  for (int kk = 0; kk < 4; kk++) {
    int k0 = kk * 32;
    f16x8 a0 = (f16x8)(half_t)0;
    if (va) a0 = *(const f16x8*)(xp + k0);
#pragma unroll
    for (int ct = 0; ct < 3; ct++) {
      f16x8 b = *(const f16x8*)(Wt + (ct * 16 + l15) * WPAD + k0 + quad * 8);
      acc[ct] = __builtin_amdgcn_mfma_f32_16x16x32_f16(a0, b, acc[ct], 0, 0, 0);
    }
  }

#pragma unroll
  for (int ct = 0; ct < 3; ct++) {
    int col = ct * 16 + l15;
    if (col < 40) {
      float bv = bc[col];
#pragma unroll
      for (int reg = 0; reg < 4; reg++) {
        int row = rb + wave * 16 + quad * 4 + reg;
        if (row < NN) out[(size_t)row * 40 + col] = acc[ct][reg] + bv;
      }
    }
  }
}

// ============================ launch ============================

extern "C" void kernel_launch(void* const* d_in, const int* in_sizes, int n_in,
                              void* d_out, int out_size, void* d_ws, size_t ws_size,
                              hipStream_t stream) {
  const float* x   = (const float*)d_in[0];
  const int*   ei  = (const int*)d_in[1];
  const float* W1  = (const float*)d_in[2];
  const float* as1 = (const float*)d_in[3];
  const float* ad1 = (const float*)d_in[4];
  const float* b1  = (const float*)d_in[5];
  const float* W2  = (const float*)d_in[6];
  const float* as2 = (const float*)d_in[7];
  const float* ad2 = (const float*)d_in[8];
  const float* b2  = (const float*)d_in[9];
  const float* Wc  = (const float*)d_in[10];
  const float* bc  = (const float*)d_in[11];
  float* out = (float*)d_out;

  const int* esrc = ei;
  const int* edst = ei + NE;

  char* w = (char*)d_ws;
  auto alloc = [&](size_t bytes) {
    void* p = (void*)w;
    w += (bytes + 255) & ~(size_t)255;
    return p;
  };
  half_t* A   = (half_t*)alloc(sizeof(half_t) * (size_t)NN * 128);  // gather target
  half_t* B   = (half_t*)alloc(sizeof(half_t) * (size_t)NN * 128);  // layer output
  float* asrc = (float*)alloc(sizeof(float) * (size_t)NN * 4);
  float* adst = (float*)alloc(sizeof(float) * (size_t)NN * 4);
  int* sbeg   = (int*)alloc(sizeof(int) * NN);
  int* send   = (int*)alloc(sizeof(int) * NN);
  unsigned int* bpk = (unsigned int*)alloc(sizeof(unsigned int) * (size_t)NBK * CAP2R);
  int* gcnt   = (int*)alloc(sizeof(int) * NBK);
  int* adj    = (int*)alloc(sizeof(int) * (size_t)NBK * CAP2);
  half_t* WT1 = (half_t*)alloc(sizeof(half_t) * 144 * 128);
  half_t* WT2 = (half_t*)alloc(sizeof(half_t) * 144 * 128);
  half_t* WTc = (half_t*)alloc(sizeof(half_t) * 48 * 128);

  // ---- zero per-bucket cursors ----
  hipMemsetAsync(gcnt, 0, sizeof(int) * NBK, stream);

  // ---- k1: edge binning ∥ weight prep ----
  k1_bin_prep<<<NBA + 12, 256, 0, stream>>>(esrc, edst, bpk, gcnt,
                                            W1, W2, Wc, as1, ad1, as2, ad2, WT1, WT2, WTc);

  // ---- k2: CSR finalize ∥ gemm1 ----
  k2_csr_gemm1<<<NBK + NBG, 256, 0, stream>>>(bpk, gcnt, sbeg, send, adj,
                                              x, WT1, A, asrc, adst);

  // ---- layer 1 aggregate ----
  k_agg<<<(NN + 3) / 4, 256, 0, stream>>>(A, sbeg, send, adj, asrc, adst, b1, B);

  // ---- layer 2 ----
  k_gemm_att<<<(NN + 63) / 64, 256, 0, stream>>>(B, WT2, A, asrc, adst);
  k_agg<<<(NN + 3) / 4, 256, 0, stream>>>(A, sbeg, send, adj, asrc, adst, b2, B);

  // ---- classifier ----
  k_classifier<<<(NN + 63) / 64, 256, 0, stream>>>(B, WTc, bc, out);
}